// Round 8
// baseline (418.988 us; speedup 1.0000x reference)
//
#include <hip/hip_runtime.h>
#include <hip/hip_bf16.h>

// GCN link predictor — pipeline (R7):
//   prep:  WT1/WT2 = fp16(W^T), cursor init                        [1 launch]
//   K1:    blocks [0,SB): bucket-scatter edges; [SB,SB+GB): gemm1 h1=fp16(x@W1)
//   K2:    per-bucket CSR finalize (rowptr/deg/dinv/adj)
//   K3:    fused agg1+gemm2: hrelu tile in LDS -> MFMA W2 -> g2=fp16(hrelu@W2*dinv)
//   K4:    agg2: z = fp16(dinv*(g2_self + sum g2[adj]) + b2)
//   K5:    decode: out[e] = dot(z[a], z[b])
//
// R2: bucket CSR build (kills 105 MB partial-line scatter).
// R3/R4: agg is L2-miss byte-rate bound (~3.4 TB/s, FETCH = 8 XCD x 25.6 MB
//        compulsory floor — invariant across 4 kernel shapes). 16-bit g halves it.
// R5: MFMA f16 GEMMs; fp16 everywhere 16-bit.
// R6: gemm dbuf + BM=64 (latency).
// R7: agg ceiling accepted; attack serialization: gemm1 || scatter in one
//     heterogeneous launch (h1 unscaled, dinv applied per-edge in agg1),
//     agg1+gemm2 fused through LDS (hbuf round trip deleted), 6 launches total.

#define DH 128
#define BUCKET_BITS 8
#define CAP 5120            // per-bucket edge capacity; mean 4096 -> 16 sigma slack
#define EPB 4096            // edges per block in scatter role
#define KPAD 40             // K1 LDS row stride (halves)
#define APAD 136            // K3 hrelu row stride (halves): 128+8, 16B-aligned
#define GBM 64              // gemm rows per block
#define NPB 8               // agg nodes per block

typedef _Float16 half8 __attribute__((ext_vector_type(8)));
typedef float floatx4 __attribute__((ext_vector_type(4)));

__device__ __forceinline__ float4 h4f(uint2 uu) {
    union { uint2 u; _Float16 h[4]; } c; c.u = uu;
    return make_float4((float)c.h[0], (float)c.h[1], (float)c.h[2], (float)c.h[3]);
}

// ---------------- prep: weight transpose+cast + cursor init ----------------

__global__ __launch_bounds__(256) void prep_kernel(
    const float* __restrict__ W1, _Float16* __restrict__ WT1,
    const float* __restrict__ W2, _Float16* __restrict__ WT2,
    int* __restrict__ cursor, int nt1, int nt2) {
    __shared__ float T[32][132];
    int b = blockIdx.x, t = threadIdx.x;
    const float* W; _Float16* WT; int K, tile;
    if (b < nt1)            { W = W1; WT = WT1; K = nt1 * 32; tile = b; }
    else if (b < nt1 + nt2) { W = W2; WT = WT2; K = nt2 * 32; tile = b - nt1; }
    else { int i = (b - nt1 - nt2) * 256 + t; cursor[i] = i * CAP; return; }
    int k0 = tile * 32;
    int kr = t >> 3, c0 = (t & 7) * 16;
#pragma unroll
    for (int j = 0; j < 4; j++) {
        float4 v = *(const float4*)&W[(size_t)(k0 + kr) * DH + c0 + j * 4];
        T[kr][c0 + j * 4 + 0] = v.x;
        T[kr][c0 + j * 4 + 1] = v.y;
        T[kr][c0 + j * 4 + 2] = v.z;
        T[kr][c0 + j * 4 + 3] = v.w;
    }
    __syncthreads();
    int n = t >> 1, ko = (t & 1) * 16;
    union { _Float16 h[16]; uint4 u4[2]; } p;
#pragma unroll
    for (int j = 0; j < 16; j++) p.h[j] = (_Float16)T[ko + j][n];
    *(uint4*)&WT[(size_t)n * K + k0 + ko]     = p.u4[0];
    *(uint4*)&WT[(size_t)n * K + k0 + ko + 8] = p.u4[1];
}

// ---------------- K1: scatter (blocks [0,SB)) + gemm1 (blocks [SB,SB+GB)) ------
// gemm1: h1[m][n] = fp16(sum_k x[m][k]*W1[k][n])  (unscaled; dinv applied in K3)
// scatter: bucket = dst>>8; packed = src | (dst&255)<<17  (valid N <= 131072)

__global__ __launch_bounds__(256) void k1_kernel(
    const float* __restrict__ A, const _Float16* __restrict__ WT,
    _Float16* __restrict__ out, int M, int K, int SB,
    const int* __restrict__ src, const int* __restrict__ dst, int E,
    int* __restrict__ cursor, int* __restrict__ pairs) {
    __shared__ __attribute__((aligned(16))) _Float16 Alds[2][GBM * KPAD];
    __shared__ __attribute__((aligned(16))) _Float16 Blds[2][128 * KPAD];
    __shared__ int hist[512];
    __shared__ int base[512];
    int t = threadIdx.x;

    if (blockIdx.x < (unsigned)SB) {
        // ---- scatter role ----
        int e0 = blockIdx.x * EPB;
        hist[t] = 0; hist[t + 256] = 0;
        __syncthreads();
        int dc[EPB / 256];
#pragma unroll
        for (int r = 0; r < EPB / 256; r++) {
            int i = e0 + r * 256 + t;
            int d = -1;
            if (i < E) { d = dst[i]; atomicAdd(&hist[d >> BUCKET_BITS], 1); }
            dc[r] = d;
        }
        __syncthreads();
#pragma unroll
        for (int b = t; b < 512; b += 256) {
            int h = hist[b];
            base[b] = h ? atomicAdd(&cursor[b], h) : 0;
        }
        __syncthreads();
        hist[t] = 0; hist[t + 256] = 0;
        __syncthreads();
#pragma unroll
        for (int r = 0; r < EPB / 256; r++) {
            int i = e0 + r * 256 + t;
            int d = dc[r];
            if (d >= 0) {
                int b = d >> BUCKET_BITS;
                int rk = atomicAdd(&hist[b], 1);
                pairs[base[b] + rk] = src[i] | ((d & 255) << 17);
            }
        }
        return;
    }

    // ---- gemm role ----
    int w = t >> 6, l = t & 63;
    int r = l & 15, q = l >> 4;
    int m0 = (blockIdx.x - SB) * GBM;
    int bn = t >> 1, bko = (t & 1) * 16;
    int am = t >> 2, ako = (t & 3) * 8;

    floatx4 acc[8];
#pragma unroll
    for (int nt = 0; nt < 8; nt++) acc[nt] = (floatx4)0.f;

    uint4 rb0, rb1;
    float4 rf0, rf1;
    union { _Float16 h[8]; uint4 u4; } ra;

    auto loadB = [&](int k0) {
        const _Float16* bs = WT + (size_t)bn * K + k0 + bko;
        rb0 = *(const uint4*)bs;
        rb1 = *(const uint4*)(bs + 8);
    };
    auto loadA = [&](int k0) {
        int m = m0 + am;
        if (m < M) {
            const float* as = A + (size_t)m * K + k0 + ako;
            rf0 = *(const float4*)as;
            rf1 = *(const float4*)(as + 4);
        } else {
            rf0 = make_float4(0.f, 0.f, 0.f, 0.f);
            rf1 = make_float4(0.f, 0.f, 0.f, 0.f);
        }
    };
    auto store = [&](int s) {
        *(uint4*)&Blds[s][bn * KPAD + bko]     = rb0;
        *(uint4*)&Blds[s][bn * KPAD + bko + 8] = rb1;
        ra.h[0] = (_Float16)rf0.x; ra.h[1] = (_Float16)rf0.y;
        ra.h[2] = (_Float16)rf0.z; ra.h[3] = (_Float16)rf0.w;
        ra.h[4] = (_Float16)rf1.x; ra.h[5] = (_Float16)rf1.y;
        ra.h[6] = (_Float16)rf1.z; ra.h[7] = (_Float16)rf1.w;
        *(uint4*)&Alds[s][am * KPAD + ako] = ra.u4;
    };

    loadB(0); loadA(0);
    store(0);
    __syncthreads();
    int cur = 0;
    for (int k0 = 0; k0 < K; k0 += 32) {
        bool has_next = (k0 + 32) < K;
        if (has_next) { loadB(k0 + 32); loadA(k0 + 32); }
        half8 afr = *(const half8*)&Alds[cur][(w * 16 + r) * KPAD + q * 8];
#pragma unroll
        for (int nt = 0; nt < 8; nt++) {
            half8 bfr = *(const half8*)&Blds[cur][(nt * 16 + r) * KPAD + q * 8];
            acc[nt] = __builtin_amdgcn_mfma_f32_16x16x32_f16(bfr, afr, acc[nt], 0, 0, 0);
        }
        if (has_next) { cur ^= 1; store(cur); }
        __syncthreads();
    }
    int m = m0 + w * 16 + r;
    if (m < M) {
#pragma unroll
        for (int nt = 0; nt < 8; nt++) {
            union { _Float16 h[4]; uint2 u; } p;
#pragma unroll
            for (int reg = 0; reg < 4; reg++)
                p.h[reg] = (_Float16)acc[nt][reg];
            *(uint2*)&out[(size_t)m * DH + nt * 16 + q * 4] = p.u;
        }
    }
}

// ---------------- K2: per-bucket CSR finalize ----------------

__global__ __launch_bounds__(256) void bucket_build_kernel(
    const int* __restrict__ pairs, const int* __restrict__ cursor,
    int* __restrict__ rowptr, int* __restrict__ deg, float* __restrict__ dinv,
    int* __restrict__ adj, int N) {
    __shared__ int cnt[256];
    __shared__ int sc[256];
    __shared__ int basep[256];
    int b = blockIdx.x;
    int t = threadIdx.x;
    int nb0 = b << BUCKET_BITS;
    int p0 = b * CAP;
    int p1 = cursor[b];
    cnt[t] = 0;
    __syncthreads();
    for (int i = p0 + t; i < p1; i += 256)
        atomicAdd(&cnt[pairs[i] >> 17], 1);
    __syncthreads();
    int c = cnt[t];
    sc[t] = c;
    __syncthreads();
    for (int off = 1; off < 256; off <<= 1) {
        int u = (t >= off) ? sc[t - off] : 0;
        __syncthreads();
        sc[t] += u;
        __syncthreads();
    }
    int ex = sc[t] - c;
    int node = nb0 + t;
    if (node < N) {
        rowptr[node] = p0 + ex;
        deg[node]    = c;
        dinv[node]   = rsqrtf((float)(c + 1));
    }
    basep[t] = p0 + ex;
    cnt[t] = 0;
    __syncthreads();
    for (int i = p0 + t; i < p1; i += 256) {
        int v = pairs[i];
        int li = v >> 17;
        int rk = atomicAdd(&cnt[li], 1);
        adj[basep[li] + rk] = v & 0x1FFFF;
    }
}

// ---------------- K3: fused agg1 + gemm2 ----------------
// Per block: 64 nodes. Phase 1 (8 groups x 32 lanes): hrelu row for each node
//   hrelu[i] = relu(dinv[i]*(h1[i]*dinv[i] + sum_j h1[j]*dinv[j]) + b1) -> LDS fp16.
// Phase 2 (4 waves): MFMA vs WT2 (global, L2-hot) -> g2 = fp16(hrelu@W2 * dinv).

__global__ __launch_bounds__(256) void k3_kernel(
    const _Float16* __restrict__ g, const int* __restrict__ rowptr,
    const int* __restrict__ deg, const int* __restrict__ adj,
    const float* __restrict__ dinv, const float* __restrict__ bias,
    const _Float16* __restrict__ WT2, _Float16* __restrict__ out, int N) {
    __shared__ __attribute__((aligned(16))) _Float16 Ah[GBM * APAD];
    int t = threadIdx.x;
    int grp = t >> 5, l = t & 31, c4 = l * 4;
    int m0 = blockIdx.x * GBM;

    for (int s = 0; s < 8; s++) {
        int row = grp * 8 + s;
        int i = m0 + row;
        uint2 pz = make_uint2(0, 0);
        if (i < N) {
            int r0 = rowptr[i], d = deg[i];
            float dv = dinv[i];
            float4 a0 = h4f(*(const uint2*)(g + (size_t)i * DH + c4));
            a0.x *= dv; a0.y *= dv; a0.z *= dv; a0.w *= dv;   // self: h1[i]*dinv[i]
            float4 a1 = make_float4(0.f, 0.f, 0.f, 0.f);
            float4 a2 = make_float4(0.f, 0.f, 0.f, 0.f);
            float4 a3 = make_float4(0.f, 0.f, 0.f, 0.f);
            int r = 0;
            for (; r + 4 <= d; r += 4) {
                int j0 = adj[r0 + r],     j1 = adj[r0 + r + 1];
                int j2 = adj[r0 + r + 2], j3 = adj[r0 + r + 3];
                float d0 = dinv[j0], d1 = dinv[j1], d2 = dinv[j2], d3 = dinv[j3];
                float4 v0 = h4f(*(const uint2*)(g + (size_t)j0 * DH + c4));
                float4 v1 = h4f(*(const uint2*)(g + (size_t)j1 * DH + c4));
                float4 v2 = h4f(*(const uint2*)(g + (size_t)j2 * DH + c4));
                float4 v3 = h4f(*(const uint2*)(g + (size_t)j3 * DH + c4));
                a0.x = fmaf(v0.x, d0, a0.x); a0.y = fmaf(v0.y, d0, a0.y);
                a0.z = fmaf(v0.z, d0, a0.z); a0.w = fmaf(v0.w, d0, a0.w);
                a1.x = fmaf(v1.x, d1, a1.x); a1.y = fmaf(v1.y, d1, a1.y);
                a1.z = fmaf(v1.z, d1, a1.z); a1.w = fmaf(v1.w, d1, a1.w);
                a2.x = fmaf(v2.x, d2, a2.x); a2.y = fmaf(v2.y, d2, a2.y);
                a2.z = fmaf(v2.z, d2, a2.z); a2.w = fmaf(v2.w, d2, a2.w);
                a3.x = fmaf(v3.x, d3, a3.x); a3.y = fmaf(v3.y, d3, a3.y);
                a3.z = fmaf(v3.z, d3, a3.z); a3.w = fmaf(v3.w, d3, a3.w);
            }
            for (; r < d; r++) {
                int j = adj[r0 + r];
                float dj = dinv[j];
                float4 v = h4f(*(const uint2*)(g + (size_t)j * DH + c4));
                a0.x = fmaf(v.x, dj, a0.x); a0.y = fmaf(v.y, dj, a0.y);
                a0.z = fmaf(v.z, dj, a0.z); a0.w = fmaf(v.w, dj, a0.w);
            }
            a0.x += a1.x + a2.x + a3.x;
            a0.y += a1.y + a2.y + a3.y;
            a0.z += a1.z + a2.z + a3.z;
            a0.w += a1.w + a2.w + a3.w;
            float4 bv = *(const float4*)(bias + c4);
            float sx = fmaxf(a0.x * dv + bv.x, 0.f);
            float sy = fmaxf(a0.y * dv + bv.y, 0.f);
            float sz = fmaxf(a0.z * dv + bv.z, 0.f);
            float sw = fmaxf(a0.w * dv + bv.w, 0.f);
            union { _Float16 h[4]; uint2 u; } p;
            p.h[0] = (_Float16)sx; p.h[1] = (_Float16)sy;
            p.h[2] = (_Float16)sz; p.h[3] = (_Float16)sw;
            pz = p.u;
        }
        *(uint2*)&Ah[row * APAD + c4] = pz;
    }
    __syncthreads();

    int w = t >> 6, l64 = t & 63;
    int rr = l64 & 15, q = l64 >> 4;
    floatx4 acc[8];
#pragma unroll
    for (int nt = 0; nt < 8; nt++) acc[nt] = (floatx4)0.f;
#pragma unroll
    for (int c = 0; c < 4; c++) {
        half8 afr = *(const half8*)&Ah[(w * 16 + rr) * APAD + c * 32 + q * 8];
#pragma unroll
        for (int nt = 0; nt < 8; nt++) {
            half8 bfr = *(const half8*)&WT2[(size_t)(nt * 16 + rr) * DH + c * 32 + q * 8];
            acc[nt] = __builtin_amdgcn_mfma_f32_16x16x32_f16(bfr, afr, acc[nt], 0, 0, 0);
        }
    }
    int m = m0 + w * 16 + rr;
    if (m < N) {
        float dv = dinv[m];
#pragma unroll
        for (int nt = 0; nt < 8; nt++) {
            union { _Float16 h[4]; uint2 u; } p;
#pragma unroll
            for (int reg = 0; reg < 4; reg++)
                p.h[reg] = (_Float16)(acc[nt][reg] * dv);
            *(uint2*)&out[(size_t)m * DH + nt * 16 + q * 4] = p.u;
        }
    }
}

// ---------------- K4: agg2: z = fp16(dinv*(g2_self + sum g2[adj]) + b2) -----------

__device__ __forceinline__ void f4acc(float4& a, const float4 v) {
    a.x += v.x; a.y += v.y; a.z += v.z; a.w += v.w;
}

__global__ __launch_bounds__(256) void agg_kernel(
    const _Float16* __restrict__ g, const int* __restrict__ rowptr,
    const int* __restrict__ deg, const int* __restrict__ adj,
    const float* __restrict__ dinv, const float* __restrict__ bias,
    _Float16* __restrict__ out, int N) {
    int grp = threadIdx.x >> 5;
    int l   = threadIdx.x & 31;
    int c4  = l * 4;
    int i = blockIdx.x * NPB + grp;
    if (i >= N) return;
    int r0 = rowptr[i];
    int d  = deg[i];
    float4 a0 = h4f(*(const uint2*)(g + (size_t)i * DH + c4));
    float4 a1 = make_float4(0.f, 0.f, 0.f, 0.f);
    float4 a2 = make_float4(0.f, 0.f, 0.f, 0.f);
    float4 a3 = make_float4(0.f, 0.f, 0.f, 0.f);
    int r = 0;
    for (; r + 4 <= d; r += 4) {
        int j0 = adj[r0 + r];
        int j1 = adj[r0 + r + 1];
        int j2 = adj[r0 + r + 2];
        int j3 = adj[r0 + r + 3];
        uint2 u0 = *(const uint2*)(g + (size_t)j0 * DH + c4);
        uint2 u1 = *(const uint2*)(g + (size_t)j1 * DH + c4);
        uint2 u2 = *(const uint2*)(g + (size_t)j2 * DH + c4);
        uint2 u3 = *(const uint2*)(g + (size_t)j3 * DH + c4);
        f4acc(a0, h4f(u0)); f4acc(a1, h4f(u1)); f4acc(a2, h4f(u2)); f4acc(a3, h4f(u3));
    }
    for (; r < d; r++) {
        int j = adj[r0 + r];
        f4acc(a0, h4f(*(const uint2*)(g + (size_t)j * DH + c4)));
    }
    f4acc(a0, a1); f4acc(a2, a3); f4acc(a0, a2);
    float dv = dinv[i];
    float4 bv = *(const float4*)(bias + c4);
    union { _Float16 h[4]; uint2 u; } p;
    p.h[0] = (_Float16)(a0.x * dv + bv.x);
    p.h[1] = (_Float16)(a0.y * dv + bv.y);
    p.h[2] = (_Float16)(a0.z * dv + bv.z);
    p.h[3] = (_Float16)(a0.w * dv + bv.w);
    *(uint2*)(out + (size_t)i * DH + c4) = p.u;
}

// ---------------- K5: decode: out[e] = dot(z[a], z[b]) over 128 (z fp16) ----------

__global__ __launch_bounds__(256) void decode_kernel(
    const _Float16* __restrict__ z, const int* __restrict__ ea, const int* __restrict__ eb,
    float* __restrict__ out, int EL) {
    int e = blockIdx.x * 8 + (threadIdx.x >> 5);
    int l = threadIdx.x & 31;
    if (e >= EL) return;
    int a = ea[e], b = eb[e];
    float4 va = h4f(*(const uint2*)(z + (size_t)a * DH + l * 4));
    float4 vb = h4f(*(const uint2*)(z + (size_t)b * DH + l * 4));
    float acc = va.x * vb.x + va.y * vb.y + va.z * vb.z + va.w * vb.w;
#pragma unroll
    for (int off = 16; off > 0; off >>= 1)
        acc += __shfl_down(acc, off, 32);
    if (l == 0) out[e] = acc;
}

// ---------------- Launch ----------------

extern "C" void kernel_launch(void* const* d_in, const int* in_sizes, int n_in,
                              void* d_out, int out_size, void* d_ws, size_t ws_size,
                              hipStream_t stream) {
    const float* x   = (const float*)d_in[0];
    const int*   ei  = (const int*)d_in[1];
    const int*   eli = (const int*)d_in[2];
    const float* W1  = (const float*)d_in[3];
    const float* b1  = (const float*)d_in[4];
    const float* W2  = (const float*)d_in[5];
    const float* b2  = (const float*)d_in[6];
    float* out = (float*)d_out;

    int DHv = in_sizes[4];                 // 128
    int DIN = in_sizes[3] / DHv;           // 256
    int N   = in_sizes[0] / DIN;           // 100000
    int E   = in_sizes[1] / 2;             // 1600000
    int EL  = in_sizes[2] / 2;             // 200000
    const int* src = ei;
    const int* dst = ei + E;
    const int* ea = eli;
    const int* eb = eli + EL;

    int NB = (N + 255) >> BUCKET_BITS;     // 391 buckets
    int SB = (E + EPB - 1) / EPB;          // 391 scatter blocks
    int GB = (N + GBM - 1) / GBM;          // 1563 gemm blocks

    // workspace carve-up (256B aligned)
    char* ws = (char*)d_ws;
    size_t off = 0;
    auto alloc = [&](size_t bytes) {
        void* p = ws + off;
        off += (bytes + 255) & ~(size_t)255;
        return p;
    };
    int*      cursor = (int*)alloc(512 * 4);
    int*      rowptr = (int*)alloc((size_t)N * 4);
    int*      deg    = (int*)alloc((size_t)N * 4);
    float*    dinv   = (float*)alloc((size_t)N * 4);
    int*      adj    = (int*)alloc((size_t)NB * CAP * 4);      // bucketed, with gaps
    _Float16* WT1    = (_Float16*)alloc((size_t)DIN * DHv * 2);
    _Float16* WT2    = (_Float16*)alloc((size_t)DHv * DHv * 2);
    _Float16* gbuf   = (_Float16*)alloc((size_t)N * DH * 2);   // h1, later z
    _Float16* hbuf   = (_Float16*)alloc((size_t)N * DH * 2);   // g2
    int*      pairs  = (int*)hbuf;   // 8 MB staging; dead before K3 writes hbuf

    int nt1 = DIN / 32, nt2 = DHv / 32;
    // prep: WT1, WT2, cursor
    prep_kernel<<<nt1 + nt2 + 2, 256, 0, stream>>>(W1, WT1, W2, WT2, cursor, nt1, nt2);
    // K1: scatter (first SB blocks) || gemm1 h1 = fp16(x@W1)
    k1_kernel<<<SB + GB, 256, 0, stream>>>(x, WT1, gbuf, N, DIN, SB,
                                           src, dst, E, cursor, pairs);
    // K2: CSR finalize
    bucket_build_kernel<<<NB, 256, 0, stream>>>(pairs, cursor, rowptr, deg, dinv, adj, N);
    // K3: fused agg1+gemm2 -> g2
    k3_kernel<<<GB, 256, 0, stream>>>(gbuf, rowptr, deg, adj, dinv, b1, WT2, hbuf, N);
    // K4: agg2 -> z (into gbuf)
    agg_kernel<<<(N + NPB - 1) / NPB, 256, 0, stream>>>(hbuf, rowptr, deg, adj, dinv, b2, gbuf, N);
    // K5: decode
    decode_kernel<<<(EL + 7) / 8, 256, 0, stream>>>(gbuf, ea, eb, out, EL);
}

// Round 9
// 380.149 us; speedup vs baseline: 1.1022x; 1.1022x over previous
//
#include <hip/hip_runtime.h>
#include <hip/hip_bf16.h>

// GCN link predictor — pipeline (R8):
//   prep:  WT1/WT2 = fp16(W^T), cursor init                        [1 launch]
//   K1:    blocks [0,SB): bucket-scatter edges; [SB,SB+GB): gemm1 h1=fp16(x@W1) (unscaled)
//   K2:    per-bucket CSR finalize (rowptr/deg/dinv/adj)
//   agg1:  hrelu = fp16(relu(dinv_i*(h1_i*dinv_i + sum_j h1_j*dinv_j) + b1))
//   gemm2: g2 = fp16((hrelu @ W2) * dinv)
//   agg2:  z = fp16(dinv*(g2_self + sum g2[adj]) + b2)
//   K5:    decode: out[e] = dot(z[a], z[b])
//
// R2: bucket CSR build (kills 105 MB partial-line scatter).
// R3/R4: agg is L2-miss byte-rate bound (~3.4 TB/s, FETCH = 8 XCD x ~24 MB
//        compulsory floor — invariant across 4 kernel shapes). 16-bit g halves it.
// R5: MFMA f16 GEMMs; fp16 everywhere 16-bit.
// R6: gemm dbuf + BM=64.
// R7: K3 (agg1+gemm2 LDS fusion) REGRESSED: 125 us vs 85 — Occ 32% vs 69%,
//     gather rate halved (64 serialized nodes/block + barrier tail). Reverted in R8;
//     kept: single prep launch, scatter||gemm1. R8 also EPB 4096->8192.

#define DH 128
#define BUCKET_BITS 8
#define CAP 5120            // per-bucket edge capacity; mean 4096 -> 16 sigma slack
#define EPB 8192            // edges per block in scatter role (runs ~84 B)
#define KPAD 40             // gemm LDS row stride (halves)
#define GBM 64              // gemm rows per block
#define NPB 8               // agg nodes per block

typedef _Float16 half8 __attribute__((ext_vector_type(8)));
typedef float floatx4 __attribute__((ext_vector_type(4)));

__device__ __forceinline__ float4 h4f(uint2 uu) {
    union { uint2 u; _Float16 h[4]; } c; c.u = uu;
    return make_float4((float)c.h[0], (float)c.h[1], (float)c.h[2], (float)c.h[3]);
}

// ---------------- prep: weight transpose+cast + cursor init ----------------

__global__ __launch_bounds__(256) void prep_kernel(
    const float* __restrict__ W1, _Float16* __restrict__ WT1,
    const float* __restrict__ W2, _Float16* __restrict__ WT2,
    int* __restrict__ cursor, int nt1, int nt2) {
    __shared__ float T[32][132];
    int b = blockIdx.x, t = threadIdx.x;
    const float* W; _Float16* WT; int K, tile;
    if (b < nt1)            { W = W1; WT = WT1; K = nt1 * 32; tile = b; }
    else if (b < nt1 + nt2) { W = W2; WT = WT2; K = nt2 * 32; tile = b - nt1; }
    else { int i = (b - nt1 - nt2) * 256 + t; cursor[i] = i * CAP; return; }
    int k0 = tile * 32;
    int kr = t >> 3, c0 = (t & 7) * 16;
#pragma unroll
    for (int j = 0; j < 4; j++) {
        float4 v = *(const float4*)&W[(size_t)(k0 + kr) * DH + c0 + j * 4];
        T[kr][c0 + j * 4 + 0] = v.x;
        T[kr][c0 + j * 4 + 1] = v.y;
        T[kr][c0 + j * 4 + 2] = v.z;
        T[kr][c0 + j * 4 + 3] = v.w;
    }
    __syncthreads();
    int n = t >> 1, ko = (t & 1) * 16;
    union { _Float16 h[16]; uint4 u4[2]; } p;
#pragma unroll
    for (int j = 0; j < 16; j++) p.h[j] = (_Float16)T[ko + j][n];
    *(uint4*)&WT[(size_t)n * K + k0 + ko]     = p.u4[0];
    *(uint4*)&WT[(size_t)n * K + k0 + ko + 8] = p.u4[1];
}

// ---------------- K1: scatter (blocks [0,SB)) + gemm1 (blocks [SB,SB+GB)) ------
// gemm1: h1[m][n] = fp16(sum_k x[m][k]*W1[k][n])  (unscaled; dinv applied in agg1)
// scatter: bucket = dst>>8; packed = src | (dst&255)<<17  (valid N <= 131072)

__global__ __launch_bounds__(256) void k1_kernel(
    const float* __restrict__ A, const _Float16* __restrict__ WT,
    _Float16* __restrict__ out, int M, int K, int SB,
    const int* __restrict__ src, const int* __restrict__ dst, int E,
    int* __restrict__ cursor, int* __restrict__ pairs) {
    __shared__ __attribute__((aligned(16))) _Float16 Alds[2][GBM * KPAD];
    __shared__ __attribute__((aligned(16))) _Float16 Blds[2][128 * KPAD];
    __shared__ int hist[512];
    __shared__ int base[512];
    int t = threadIdx.x;

    if (blockIdx.x < (unsigned)SB) {
        // ---- scatter role ----
        int e0 = blockIdx.x * EPB;
        hist[t] = 0; hist[t + 256] = 0;
        __syncthreads();
        int dc[EPB / 256];
#pragma unroll
        for (int r = 0; r < EPB / 256; r++) {
            int i = e0 + r * 256 + t;
            int d = -1;
            if (i < E) { d = dst[i]; atomicAdd(&hist[d >> BUCKET_BITS], 1); }
            dc[r] = d;
        }
        __syncthreads();
#pragma unroll
        for (int b = t; b < 512; b += 256) {
            int h = hist[b];
            base[b] = h ? atomicAdd(&cursor[b], h) : 0;
        }
        __syncthreads();
        hist[t] = 0; hist[t + 256] = 0;
        __syncthreads();
#pragma unroll
        for (int r = 0; r < EPB / 256; r++) {
            int i = e0 + r * 256 + t;
            int d = dc[r];
            if (d >= 0) {
                int b = d >> BUCKET_BITS;
                int rk = atomicAdd(&hist[b], 1);
                pairs[base[b] + rk] = src[i] | ((d & 255) << 17);
            }
        }
        return;
    }

    // ---- gemm role ----
    int w = t >> 6, l = t & 63;
    int r = l & 15, q = l >> 4;
    int m0 = (blockIdx.x - SB) * GBM;
    int bn = t >> 1, bko = (t & 1) * 16;
    int am = t >> 2, ako = (t & 3) * 8;

    floatx4 acc[8];
#pragma unroll
    for (int nt = 0; nt < 8; nt++) acc[nt] = (floatx4)0.f;

    uint4 rb0, rb1;
    float4 rf0, rf1;
    union { _Float16 h[8]; uint4 u4; } ra;

    auto loadB = [&](int k0) {
        const _Float16* bs = WT + (size_t)bn * K + k0 + bko;
        rb0 = *(const uint4*)bs;
        rb1 = *(const uint4*)(bs + 8);
    };
    auto loadA = [&](int k0) {
        int m = m0 + am;
        if (m < M) {
            const float* as = A + (size_t)m * K + k0 + ako;
            rf0 = *(const float4*)as;
            rf1 = *(const float4*)(as + 4);
        } else {
            rf0 = make_float4(0.f, 0.f, 0.f, 0.f);
            rf1 = make_float4(0.f, 0.f, 0.f, 0.f);
        }
    };
    auto store = [&](int s) {
        *(uint4*)&Blds[s][bn * KPAD + bko]     = rb0;
        *(uint4*)&Blds[s][bn * KPAD + bko + 8] = rb1;
        ra.h[0] = (_Float16)rf0.x; ra.h[1] = (_Float16)rf0.y;
        ra.h[2] = (_Float16)rf0.z; ra.h[3] = (_Float16)rf0.w;
        ra.h[4] = (_Float16)rf1.x; ra.h[5] = (_Float16)rf1.y;
        ra.h[6] = (_Float16)rf1.z; ra.h[7] = (_Float16)rf1.w;
        *(uint4*)&Alds[s][am * KPAD + ako] = ra.u4;
    };

    loadB(0); loadA(0);
    store(0);
    __syncthreads();
    int cur = 0;
    for (int k0 = 0; k0 < K; k0 += 32) {
        bool has_next = (k0 + 32) < K;
        if (has_next) { loadB(k0 + 32); loadA(k0 + 32); }
        half8 afr = *(const half8*)&Alds[cur][(w * 16 + r) * KPAD + q * 8];
#pragma unroll
        for (int nt = 0; nt < 8; nt++) {
            half8 bfr = *(const half8*)&Blds[cur][(nt * 16 + r) * KPAD + q * 8];
            acc[nt] = __builtin_amdgcn_mfma_f32_16x16x32_f16(bfr, afr, acc[nt], 0, 0, 0);
        }
        if (has_next) { cur ^= 1; store(cur); }
        __syncthreads();
    }
    int m = m0 + w * 16 + r;
    if (m < M) {
#pragma unroll
        for (int nt = 0; nt < 8; nt++) {
            union { _Float16 h[4]; uint2 u; } p;
#pragma unroll
            for (int reg = 0; reg < 4; reg++)
                p.h[reg] = (_Float16)acc[nt][reg];
            *(uint2*)&out[(size_t)m * DH + nt * 16 + q * 4] = p.u;
        }
    }
}

// ---------------- K2: per-bucket CSR finalize ----------------

__global__ __launch_bounds__(256) void bucket_build_kernel(
    const int* __restrict__ pairs, const int* __restrict__ cursor,
    int* __restrict__ rowptr, int* __restrict__ deg, float* __restrict__ dinv,
    int* __restrict__ adj, int N) {
    __shared__ int cnt[256];
    __shared__ int sc[256];
    __shared__ int basep[256];
    int b = blockIdx.x;
    int t = threadIdx.x;
    int nb0 = b << BUCKET_BITS;
    int p0 = b * CAP;
    int p1 = cursor[b];
    cnt[t] = 0;
    __syncthreads();
    for (int i = p0 + t; i < p1; i += 256)
        atomicAdd(&cnt[pairs[i] >> 17], 1);
    __syncthreads();
    int c = cnt[t];
    sc[t] = c;
    __syncthreads();
    for (int off = 1; off < 256; off <<= 1) {
        int u = (t >= off) ? sc[t - off] : 0;
        __syncthreads();
        sc[t] += u;
        __syncthreads();
    }
    int ex = sc[t] - c;
    int node = nb0 + t;
    if (node < N) {
        rowptr[node] = p0 + ex;
        deg[node]    = c;
        dinv[node]   = rsqrtf((float)(c + 1));
    }
    basep[t] = p0 + ex;
    cnt[t] = 0;
    __syncthreads();
    for (int i = p0 + t; i < p1; i += 256) {
        int v = pairs[i];
        int li = v >> 17;
        int rk = atomicAdd(&cnt[li], 1);
        adj[basep[li] + rk] = v & 0x1FFFF;
    }
}

// ---------------- agg (templated) ----------------
// SCALED=1 (agg1): acc = h1_i*dinv_i + sum_j h1_j*dinv_j;  out = relu(acc*dinv_i + b)
// SCALED=0 (agg2): acc = g2_i + sum_j g2_j (g2 pre-scaled);  out = acc*dinv_i + b
// 32-lane group per node, uint2 (4 halves)/lane; 4-edge unroll, 4 fp32 acc chains.

template <int SCALED>
__global__ __launch_bounds__(256) void agg_kernel(
    const _Float16* __restrict__ g, const int* __restrict__ rowptr,
    const int* __restrict__ deg, const int* __restrict__ adj,
    const float* __restrict__ dinv, const float* __restrict__ bias,
    _Float16* __restrict__ out, int N) {
    int grp = threadIdx.x >> 5;
    int l   = threadIdx.x & 31;
    int c4  = l * 4;
    int i = blockIdx.x * NPB + grp;
    if (i >= N) return;
    int r0 = rowptr[i];
    int d  = deg[i];
    float dv = dinv[i];
    float4 a0 = h4f(*(const uint2*)(g + (size_t)i * DH + c4));
    if (SCALED) { a0.x *= dv; a0.y *= dv; a0.z *= dv; a0.w *= dv; }
    float4 a1 = make_float4(0.f, 0.f, 0.f, 0.f);
    float4 a2 = make_float4(0.f, 0.f, 0.f, 0.f);
    float4 a3 = make_float4(0.f, 0.f, 0.f, 0.f);
    int r = 0;
    for (; r + 4 <= d; r += 4) {
        int j0 = adj[r0 + r],     j1 = adj[r0 + r + 1];
        int j2 = adj[r0 + r + 2], j3 = adj[r0 + r + 3];
        float4 v0 = h4f(*(const uint2*)(g + (size_t)j0 * DH + c4));
        float4 v1 = h4f(*(const uint2*)(g + (size_t)j1 * DH + c4));
        float4 v2 = h4f(*(const uint2*)(g + (size_t)j2 * DH + c4));
        float4 v3 = h4f(*(const uint2*)(g + (size_t)j3 * DH + c4));
        if (SCALED) {
            float d0 = dinv[j0], d1 = dinv[j1], d2 = dinv[j2], d3 = dinv[j3];
            a0.x = fmaf(v0.x, d0, a0.x); a0.y = fmaf(v0.y, d0, a0.y);
            a0.z = fmaf(v0.z, d0, a0.z); a0.w = fmaf(v0.w, d0, a0.w);
            a1.x = fmaf(v1.x, d1, a1.x); a1.y = fmaf(v1.y, d1, a1.y);
            a1.z = fmaf(v1.z, d1, a1.z); a1.w = fmaf(v1.w, d1, a1.w);
            a2.x = fmaf(v2.x, d2, a2.x); a2.y = fmaf(v2.y, d2, a2.y);
            a2.z = fmaf(v2.z, d2, a2.z); a2.w = fmaf(v2.w, d2, a2.w);
            a3.x = fmaf(v3.x, d3, a3.x); a3.y = fmaf(v3.y, d3, a3.y);
            a3.z = fmaf(v3.z, d3, a3.z); a3.w = fmaf(v3.w, d3, a3.w);
        } else {
            a0.x += v0.x; a0.y += v0.y; a0.z += v0.z; a0.w += v0.w;
            a1.x += v1.x; a1.y += v1.y; a1.z += v1.z; a1.w += v1.w;
            a2.x += v2.x; a2.y += v2.y; a2.z += v2.z; a2.w += v2.w;
            a3.x += v3.x; a3.y += v3.y; a3.z += v3.z; a3.w += v3.w;
        }
    }
    for (; r < d; r++) {
        int j = adj[r0 + r];
        float4 v = h4f(*(const uint2*)(g + (size_t)j * DH + c4));
        float dj = SCALED ? dinv[j] : 1.0f;
        a0.x = fmaf(v.x, dj, a0.x); a0.y = fmaf(v.y, dj, a0.y);
        a0.z = fmaf(v.z, dj, a0.z); a0.w = fmaf(v.w, dj, a0.w);
    }
    a0.x += a1.x + a2.x + a3.x;
    a0.y += a1.y + a2.y + a3.y;
    a0.z += a1.z + a2.z + a3.z;
    a0.w += a1.w + a2.w + a3.w;
    float4 bv = *(const float4*)(bias + c4);
    float sx = a0.x * dv + bv.x;
    float sy = a0.y * dv + bv.y;
    float sz = a0.z * dv + bv.z;
    float sw = a0.w * dv + bv.w;
    if (SCALED) {
        sx = fmaxf(sx, 0.f); sy = fmaxf(sy, 0.f);
        sz = fmaxf(sz, 0.f); sw = fmaxf(sw, 0.f);
    }
    union { _Float16 h[4]; uint2 u; } p;
    p.h[0] = (_Float16)sx; p.h[1] = (_Float16)sy;
    p.h[2] = (_Float16)sz; p.h[3] = (_Float16)sw;
    *(uint2*)(out + (size_t)i * DH + c4) = p.u;
}

// ---------------- gemm2: g2 = fp16((hrelu @ W2) * dinv), A fp16 ----------------

__global__ __launch_bounds__(256) void gemm2_kernel(
    const _Float16* __restrict__ A, const _Float16* __restrict__ WT,
    const float* __restrict__ dinv, _Float16* __restrict__ out,
    int M, int K) {
    __shared__ __attribute__((aligned(16))) _Float16 Alds[2][GBM * KPAD];
    __shared__ __attribute__((aligned(16))) _Float16 Blds[2][128 * KPAD];
    int t = threadIdx.x;
    int w = t >> 6, l = t & 63;
    int r = l & 15, q = l >> 4;
    int m0 = blockIdx.x * GBM;
    int bn = t >> 1, bko = (t & 1) * 16;
    int am = t >> 2, ako = (t & 3) * 8;

    floatx4 acc[8];
#pragma unroll
    for (int nt = 0; nt < 8; nt++) acc[nt] = (floatx4)0.f;

    uint4 rb0, rb1;
    union { _Float16 h[8]; uint4 u4; } ra;

    auto loadB = [&](int k0) {
        const _Float16* bs = WT + (size_t)bn * K + k0 + bko;
        rb0 = *(const uint4*)bs;
        rb1 = *(const uint4*)(bs + 8);
    };
    auto loadA = [&](int k0) {
        int m = m0 + am;
        if (m < M) ra.u4 = *(const uint4*)(A + (size_t)m * K + k0 + ako);
        else ra.u4 = make_uint4(0, 0, 0, 0);
    };
    auto store = [&](int s) {
        *(uint4*)&Blds[s][bn * KPAD + bko]     = rb0;
        *(uint4*)&Blds[s][bn * KPAD + bko + 8] = rb1;
        *(uint4*)&Alds[s][am * KPAD + ako] = ra.u4;
    };

    loadB(0); loadA(0);
    store(0);
    __syncthreads();
    int cur = 0;
    for (int k0 = 0; k0 < K; k0 += 32) {
        bool has_next = (k0 + 32) < K;
        if (has_next) { loadB(k0 + 32); loadA(k0 + 32); }
        half8 afr = *(const half8*)&Alds[cur][(w * 16 + r) * KPAD + q * 8];
#pragma unroll
        for (int nt = 0; nt < 8; nt++) {
            half8 bfr = *(const half8*)&Blds[cur][(nt * 16 + r) * KPAD + q * 8];
            acc[nt] = __builtin_amdgcn_mfma_f32_16x16x32_f16(bfr, afr, acc[nt], 0, 0, 0);
        }
        if (has_next) { cur ^= 1; store(cur); }
        __syncthreads();
    }
    int m = m0 + w * 16 + r;
    if (m < M) {
        float dv = dinv[m];
#pragma unroll
        for (int nt = 0; nt < 8; nt++) {
            union { _Float16 h[4]; uint2 u; } p;
#pragma unroll
            for (int reg = 0; reg < 4; reg++)
                p.h[reg] = (_Float16)(acc[nt][reg] * dv);
            *(uint2*)&out[(size_t)m * DH + nt * 16 + q * 4] = p.u;
        }
    }
}

// ---------------- K5: decode: out[e] = dot(z[a], z[b]) over 128 (z fp16) ----------

__global__ __launch_bounds__(256) void decode_kernel(
    const _Float16* __restrict__ z, const int* __restrict__ ea, const int* __restrict__ eb,
    float* __restrict__ out, int EL) {
    int e = blockIdx.x * 8 + (threadIdx.x >> 5);
    int l = threadIdx.x & 31;
    if (e >= EL) return;
    int a = ea[e], b = eb[e];
    float4 va = h4f(*(const uint2*)(z + (size_t)a * DH + l * 4));
    float4 vb = h4f(*(const uint2*)(z + (size_t)b * DH + l * 4));
    float acc = va.x * vb.x + va.y * vb.y + va.z * vb.z + va.w * vb.w;
#pragma unroll
    for (int off = 16; off > 0; off >>= 1)
        acc += __shfl_down(acc, off, 32);
    if (l == 0) out[e] = acc;
}

// ---------------- Launch ----------------

extern "C" void kernel_launch(void* const* d_in, const int* in_sizes, int n_in,
                              void* d_out, int out_size, void* d_ws, size_t ws_size,
                              hipStream_t stream) {
    const float* x   = (const float*)d_in[0];
    const int*   ei  = (const int*)d_in[1];
    const int*   eli = (const int*)d_in[2];
    const float* W1  = (const float*)d_in[3];
    const float* b1  = (const float*)d_in[4];
    const float* W2  = (const float*)d_in[5];
    const float* b2  = (const float*)d_in[6];
    float* out = (float*)d_out;

    int DHv = in_sizes[4];                 // 128
    int DIN = in_sizes[3] / DHv;           // 256
    int N   = in_sizes[0] / DIN;           // 100000
    int E   = in_sizes[1] / 2;             // 1600000
    int EL  = in_sizes[2] / 2;             // 200000
    const int* src = ei;
    const int* dst = ei + E;
    const int* ea = eli;
    const int* eb = eli + EL;

    int NB = (N + 255) >> BUCKET_BITS;     // 391 buckets
    int SB = (E + EPB - 1) / EPB;          // 196 scatter blocks
    int GB = (N + GBM - 1) / GBM;          // 1563 gemm blocks

    // workspace carve-up (256B aligned)
    char* ws = (char*)d_ws;
    size_t off = 0;
    auto alloc = [&](size_t bytes) {
        void* p = ws + off;
        off += (bytes + 255) & ~(size_t)255;
        return p;
    };
    int*      cursor = (int*)alloc(512 * 4);
    int*      rowptr = (int*)alloc((size_t)N * 4);
    int*      deg    = (int*)alloc((size_t)N * 4);
    float*    dinv   = (float*)alloc((size_t)N * 4);
    int*      adj    = (int*)alloc((size_t)NB * CAP * 4);      // bucketed, with gaps
    _Float16* WT1    = (_Float16*)alloc((size_t)DIN * DHv * 2);
    _Float16* WT2    = (_Float16*)alloc((size_t)DHv * DHv * 2);
    _Float16* gbuf   = (_Float16*)alloc((size_t)N * DH * 2);   // h1 -> g2
    _Float16* hbuf   = (_Float16*)alloc((size_t)N * DH * 2);   // hrelu -> z
    int*      pairs  = (int*)hbuf;   // 8 MB staging; consumed by K2 before agg1 writes hbuf

    int nt1 = DIN / 32, nt2 = DHv / 32;
    // prep: WT1, WT2, cursor
    prep_kernel<<<nt1 + nt2 + 2, 256, 0, stream>>>(W1, WT1, W2, WT2, cursor, nt1, nt2);
    // K1: scatter (first SB blocks) || gemm1 h1 = fp16(x@W1) unscaled
    k1_kernel<<<SB + GB, 256, 0, stream>>>(x, WT1, gbuf, N, DIN, SB,
                                           src, dst, E, cursor, pairs);
    // K2: CSR finalize
    bucket_build_kernel<<<NB, 256, 0, stream>>>(pairs, cursor, rowptr, deg, dinv, adj, N);
    // agg1: hrelu (per-edge dinv scaling, relu)
    agg_kernel<1><<<(N + NPB - 1) / NPB, 256, 0, stream>>>(gbuf, rowptr, deg, adj, dinv, b1, hbuf, N);
    // gemm2: g2 = fp16((hrelu @ W2) * dinv)
    gemm2_kernel<<<GB, 256, 0, stream>>>(hbuf, WT2, dinv, gbuf, N, DHv);
    // agg2: z = fp16(dinv*(g2_self + sum g2[adj]) + b2)
    agg_kernel<0><<<(N + NPB - 1) / NPB, 256, 0, stream>>>(gbuf, rowptr, deg, adj, dinv, b2, hbuf, N);
    // decode
    decode_kernel<<<(EL + 7) / 8, 256, 0, stream>>>(hbuf, ea, eb, out, EL);
}